// Round 2
// baseline (161.123 us; speedup 1.0000x reference)
//
#include <hip/hip_runtime.h>
#include <hip/hip_bf16.h>

// InfoNCE fused: loss = (1/N) sum_i [ log(sum_j exp(sim_ij)) - sim_ii ]
// sim = (z1/||z1||)@(z2/||z2||)^T / tau.  logits=[pos, diag-masked row] with
// pos == sim_ii => lse over the FULL row (diagonal included).
//
// z1s = bf16(z1n * log2(e)/tau) so exp(sim) = exp2(MFMA output); values in
// [-29,29] in log2 domain -> plain fp32 sum of exp2, no online max needed.
//
// R2: 64 rows/wave (4 A-frag sets in regs, 4x less LDS B-traffic),
// fragment-ordered LDS (reads at lane*16, writes at tid*16 -> conflict-free),
// double-buffered staging (1 barrier/chunk), 3 dispatches (no memsets).

typedef __bf16  bf16x8 __attribute__((ext_vector_type(8)));
typedef float   f32x4  __attribute__((ext_vector_type(4)));

#define EXP2F(x) exp2f(x)   // -> v_exp_f32

#define DDIM   64
#define ROWB   128          // bytes per bf16 row
#define NW     4            // waves per block
#define WROWS  64           // rows per wave (4 x 16-row MFMA sets)
#define BM     (NW * WROWS) // 256 rows per block
#define CHUNK  64           // z2 cols staged per iteration
#define CS     8            // column splits (grid.y)
#define TILEB  2048         // bytes per 16-col fragment-ordered tile
#define BUFB   (4 * TILEB)  // 8 KB per buffer

// ---------------------------------------------------------------- normalize
// One wave per row; handles both z1 (scaled) and z2. out = [z1s | z2s].
__global__ __launch_bounds__(256) void norm_both_kernel(
    const float* __restrict__ z1, const float* __restrict__ z2,
    __hip_bfloat16* __restrict__ out, float scale1, int N)
{
    int gr   = (blockIdx.x * 256 + threadIdx.x) >> 6;   // global row in [0, 2N)
    int lane = threadIdx.x & 63;
    const float* src = (gr < N) ? (z1 + (size_t)gr * DDIM)
                                : (z2 + (size_t)(gr - N) * DDIM);
    float scale = (gr < N) ? scale1 : 1.0f;
    float v  = src[lane];
    float ss = v * v;
    #pragma unroll
    for (int off = 32; off; off >>= 1) ss += __shfl_xor(ss, off);
    float n = fmaxf(sqrtf(ss), 1e-12f);
    out[(size_t)gr * DDIM + lane] = __float2bfloat16((v / n) * scale);
}

// ---------------------------------------------------------------- main
__global__ __launch_bounds__(256) void infonce_main_kernel(
    const __hip_bfloat16* __restrict__ z1s,
    const __hip_bfloat16* __restrict__ z2s,
    float* __restrict__ partial,   // [CS][N] partial rowsums of 2^C
    float* __restrict__ posv,      // C_ii (log2-domain positive logit)
    int N)
{
    __shared__ char lds[2 * BUFB];

    const int tid  = threadIdx.x;
    const int wave = tid >> 6;
    const int lane = tid & 63;
    const int q    = lane >> 4;
    const int l15  = lane & 15;

    const int colspan = N / CS;
    const int c0      = blockIdx.y * colspan;
    const int wr      = blockIdx.x * BM + wave * WROWS;

    // ---- A fragments for 4 row-sets (held in registers for the whole sweep)
    bf16x8 a0[4], a1[4];
    #pragma unroll
    for (int s = 0; s < 4; ++s) {
        const char* ab = (const char*)z1s + (size_t)(wr + s * 16 + l15) * ROWB + q * 16;
        a0[s] = *(const bf16x8*)(ab);
        a1[s] = *(const bf16x8*)(ab + 64);
    }

    float sum[16];
    #pragma unroll
    for (int k = 0; k < 16; ++k) sum[k] = 0.f;

    // ---- staging map: thread stages fragment-slots gs = tid, tid+256.
    // slot gs -> tile = gs>>7, s = gs&127, row = tile*16 + (s&15),
    // piece p = ((s>>6)<<2) | ((s>>4)&3); LDS offset = gs*16 (thread-linear).
    const int gsA = tid, gsB = tid + 256;
    const int rowA = ((gsA >> 7) << 4) | (gsA & 15);
    const int rowB = ((gsB >> 7) << 4) | (gsB & 15);
    const int pA = (((gsA & 127) >> 6) << 2) | (((gsA & 127) >> 4) & 3);
    const int pB = (((gsB & 127) >> 6) << 2) | (((gsB & 127) >> 4) & 3);
    const char* z2b = (const char*)z2s;

    // prologue: stage chunk 0 into buffer 0
    *(float4*)(lds + gsA * 16) = *(const float4*)(z2b + (size_t)(c0 + rowA) * ROWB + pA * 16);
    *(float4*)(lds + gsB * 16) = *(const float4*)(z2b + (size_t)(c0 + rowB) * ROWB + pB * 16);
    __syncthreads();

    int pb = 0;
    for (int cc = 0; cc < colspan; cc += CHUNK) {
        // issue next chunk's global loads early (latency hidden by compute)
        float4 vA, vB;
        const bool has_next = (cc + CHUNK) < colspan;
        if (has_next) {
            const int nc = c0 + cc + CHUNK;
            vA = *(const float4*)(z2b + (size_t)(nc + rowA) * ROWB + pA * 16);
            vB = *(const float4*)(z2b + (size_t)(nc + rowB) * ROWB + pB * 16);
        }

        const char* buf = lds + pb * BUFB;
        #pragma unroll
        for (int ct = 0; ct < 4; ++ct) {
            const char* bb = buf + ct * TILEB + lane * 16;   // identity pattern
            bf16x8 b0 = *(const bf16x8*)(bb);
            bf16x8 b1 = *(const bf16x8*)(bb + 1024);
            const int cg = c0 + cc + ct * 16;
            #pragma unroll
            for (int s = 0; s < 4; ++s) {
                f32x4 acc = {0.f, 0.f, 0.f, 0.f};
                acc = __builtin_amdgcn_mfma_f32_16x16x32_bf16(a0[s], b0, acc, 0, 0, 0);
                acc = __builtin_amdgcn_mfma_f32_16x16x32_bf16(a1[s], b1, acc, 0, 0, 0);
                if (cg == wr + s * 16) {       // diagonal tile (wave-uniform, rare)
                    // C/D: col = lane&15, row = q*4 + reg
                    #pragma unroll
                    for (int i = 0; i < 4; ++i)
                        if (l15 == q * 4 + i) posv[cg + q * 4 + i] = acc[i];
                }
                sum[s * 4 + 0] += EXP2F(acc[0]);
                sum[s * 4 + 1] += EXP2F(acc[1]);
                sum[s * 4 + 2] += EXP2F(acc[2]);
                sum[s * 4 + 3] += EXP2F(acc[3]);
            }
        }

        if (has_next) {
            char* nbuf = lds + (pb ^ 1) * BUFB;
            *(float4*)(nbuf + gsA * 16) = vA;
            *(float4*)(nbuf + gsB * 16) = vB;
        }
        __syncthreads();
        pb ^= 1;
    }

    // reduce each of the 16 row-sums across the 16 lanes of the quad
    #pragma unroll
    for (int k = 0; k < 16; ++k) {
        float v = sum[k];
        #pragma unroll
        for (int off = 1; off < 16; off <<= 1) v += __shfl_xor(v, off);
        sum[k] = v;
    }
    if (l15 == 0) {
        float* dst = partial + (size_t)blockIdx.y * N + wr;
        #pragma unroll
        for (int s = 0; s < 4; ++s)
            #pragma unroll
            for (int i = 0; i < 4; ++i)
                dst[s * 16 + q * 4 + i] = sum[s * 4 + i];
    }
}

// ---------------------------------------------------------------- finalize
// Single block: sums CS partials per row, lse - pos, block-reduce, write out.
__global__ __launch_bounds__(1024) void finalize_kernel(
    const float* __restrict__ partial, const float* __restrict__ posv,
    float* __restrict__ out, int N)
{
    __shared__ float red[16];
    float acc = 0.f;
    for (int base = 0; base < N; base += 1024) {
        int row = base + threadIdx.x;
        float s = 0.f;
        #pragma unroll
        for (int c = 0; c < CS; ++c) s += partial[(size_t)c * N + row];
        acc += log2f(s) - posv[row];
    }
    #pragma unroll
    for (int off = 32; off; off >>= 1) acc += __shfl_xor(acc, off);
    int wave = threadIdx.x >> 6, lane = threadIdx.x & 63;
    if (lane == 0) red[wave] = acc;
    __syncthreads();
    if (wave == 0) {
        float v = (lane < 16) ? red[lane] : 0.f;
        #pragma unroll
        for (int off = 8; off; off >>= 1) v += __shfl_xor(v, off);
        if (lane == 0) *out = 0.69314718055994531f * v / (float)N;
    }
}

// ---------------------------------------------------------------- launch
extern "C" void kernel_launch(void* const* d_in, const int* in_sizes, int n_in,
                              void* d_out, int out_size, void* d_ws, size_t ws_size,
                              hipStream_t stream)
{
    const float* z1 = (const float*)d_in[0];
    const float* z2 = (const float*)d_in[1];
    const int N = in_sizes[0] / DDIM;   // 16384

    char* ws = (char*)d_ws;
    __hip_bfloat16* z1s = (__hip_bfloat16*)ws;                  // N*128 B
    __hip_bfloat16* z2s = z1s + (size_t)N * DDIM;               // N*128 B
    float* partial = (float*)(ws + 2 * (size_t)N * ROWB);       // CS*N*4 B
    float* posv    = partial + (size_t)CS * N;                  // N*4 B

    const float kScale = 28.853900817779268f;   // log2(e) / 0.05

    norm_both_kernel<<<2 * N / 4, 256, 0, stream>>>(z1, z2, z1s, kScale, N);

    dim3 grid(N / BM, CS);
    infonce_main_kernel<<<grid, NW * 64, 0, stream>>>(z1s, z2s, partial, posv, N);

    finalize_kernel<<<1, 1024, 0, stream>>>(partial, posv, (float*)d_out, N);
}

// Round 3
// 128.420 us; speedup vs baseline: 1.2547x; 1.2547x over previous
//
#include <hip/hip_runtime.h>
#include <hip/hip_bf16.h>

// InfoNCE fused: loss = (1/N) sum_i [ log(sum_j exp(sim_ij)) - sim_ii ]
// sim = (z1/||z1||)@(z2/||z2||)^T / tau.  logits=[pos, diag-masked row] with
// pos == sim_ii => lse over the FULL row (diagonal included).
//
// z1s = bf16(z1n * log2(e)/tau) so exp(sim) = exp2(MFMA output); values in
// [-29,29] in log2 domain -> raw v_exp_f32 is safe (no denorm/overflow), so
// we use __builtin_amdgcn_exp2f (1 instr) NOT libm exp2f (~10 instrs -- the
// R2 regression: VALU-busy time tripled).
//
// R3: restore raw exp2 builtin; CS=16 for 4 blocks/CU occupancy; parallel
// finalize (64 blocks + atomicAdd). Keep R2's conflict-free fragment-ordered
// LDS + 64 rows/wave register reuse + double-buffered staging.

typedef __bf16  bf16x8 __attribute__((ext_vector_type(8)));
typedef float   f32x4  __attribute__((ext_vector_type(4)));

#if __has_builtin(__builtin_amdgcn_exp2f)
#define EXP2F(x) __builtin_amdgcn_exp2f(x)   // raw v_exp_f32
#else
#define EXP2F(x) exp2f(x)
#endif
#if __has_builtin(__builtin_amdgcn_logf)
#define LOG2F(x) __builtin_amdgcn_logf(x)    // raw v_log_f32
#else
#define LOG2F(x) log2f(x)
#endif

#define DDIM   64
#define ROWB   128          // bytes per bf16 row
#define NW     4            // waves per block
#define WROWS  64           // rows per wave (4 x 16-row MFMA sets)
#define BM     (NW * WROWS) // 256 rows per block
#define CHUNK  64           // z2 cols staged per iteration
#define CS     16           // column splits (grid.y) -> 1024 blocks = 4/CU
#define TILEB  2048         // bytes per 16-col fragment-ordered tile
#define BUFB   (4 * TILEB)  // 8 KB per buffer

// ---------------------------------------------------------------- normalize
// One wave per row; handles both z1 (scaled) and z2. out = [z1s | z2s].
__global__ __launch_bounds__(256) void norm_both_kernel(
    const float* __restrict__ z1, const float* __restrict__ z2,
    __hip_bfloat16* __restrict__ out, float scale1, int N)
{
    int gr   = (blockIdx.x * 256 + threadIdx.x) >> 6;   // global row in [0, 2N)
    int lane = threadIdx.x & 63;
    const float* src = (gr < N) ? (z1 + (size_t)gr * DDIM)
                                : (z2 + (size_t)(gr - N) * DDIM);
    float scale = (gr < N) ? scale1 : 1.0f;
    float v  = src[lane];
    float ss = v * v;
    #pragma unroll
    for (int off = 32; off; off >>= 1) ss += __shfl_xor(ss, off);
    float n = fmaxf(sqrtf(ss), 1e-12f);
    out[(size_t)gr * DDIM + lane] = __float2bfloat16((v / n) * scale);
}

// ---------------------------------------------------------------- main
__global__ __launch_bounds__(256) void infonce_main_kernel(
    const __hip_bfloat16* __restrict__ z1s,
    const __hip_bfloat16* __restrict__ z2s,
    float* __restrict__ partial,   // [CS][N] partial rowsums of 2^C
    float* __restrict__ posv,      // C_ii (log2-domain positive logit)
    int N)
{
    __shared__ char lds[2 * BUFB];

    const int tid  = threadIdx.x;
    const int wave = tid >> 6;
    const int lane = tid & 63;
    const int q    = lane >> 4;
    const int l15  = lane & 15;

    const int colspan = N / CS;
    const int c0      = blockIdx.y * colspan;
    const int wr      = blockIdx.x * BM + wave * WROWS;

    // ---- A fragments for 4 row-sets (held in registers for the whole sweep)
    bf16x8 a0[4], a1[4];
    #pragma unroll
    for (int s = 0; s < 4; ++s) {
        const char* ab = (const char*)z1s + (size_t)(wr + s * 16 + l15) * ROWB + q * 16;
        a0[s] = *(const bf16x8*)(ab);
        a1[s] = *(const bf16x8*)(ab + 64);
    }

    float sum[16];
    #pragma unroll
    for (int k = 0; k < 16; ++k) sum[k] = 0.f;

    // ---- staging map: thread stages fragment-slots gs = tid, tid+256.
    // slot gs -> tile = gs>>7, s = gs&127, row = tile*16 + (s&15),
    // piece p = ((s>>6)<<2) | ((s>>4)&3); LDS offset = gs*16 (thread-linear).
    const int gsA = tid, gsB = tid + 256;
    const int rowA = ((gsA >> 7) << 4) | (gsA & 15);
    const int rowB = ((gsB >> 7) << 4) | (gsB & 15);
    const int pA = (((gsA & 127) >> 6) << 2) | (((gsA & 127) >> 4) & 3);
    const int pB = (((gsB & 127) >> 6) << 2) | (((gsB & 127) >> 4) & 3);
    const char* z2b = (const char*)z2s;

    // prologue: stage chunk 0 into buffer 0
    *(float4*)(lds + gsA * 16) = *(const float4*)(z2b + (size_t)(c0 + rowA) * ROWB + pA * 16);
    *(float4*)(lds + gsB * 16) = *(const float4*)(z2b + (size_t)(c0 + rowB) * ROWB + pB * 16);
    __syncthreads();

    int pb = 0;
    for (int cc = 0; cc < colspan; cc += CHUNK) {
        // issue next chunk's global loads early (latency hidden by compute)
        float4 vA, vB;
        const bool has_next = (cc + CHUNK) < colspan;
        if (has_next) {
            const int nc = c0 + cc + CHUNK;
            vA = *(const float4*)(z2b + (size_t)(nc + rowA) * ROWB + pA * 16);
            vB = *(const float4*)(z2b + (size_t)(nc + rowB) * ROWB + pB * 16);
        }

        const char* buf = lds + pb * BUFB;
        #pragma unroll
        for (int ct = 0; ct < 4; ++ct) {
            const char* bb = buf + ct * TILEB + lane * 16;   // identity pattern
            bf16x8 b0 = *(const bf16x8*)(bb);
            bf16x8 b1 = *(const bf16x8*)(bb + 1024);
            const int cg = c0 + cc + ct * 16;
            #pragma unroll
            for (int s = 0; s < 4; ++s) {
                f32x4 acc = {0.f, 0.f, 0.f, 0.f};
                acc = __builtin_amdgcn_mfma_f32_16x16x32_bf16(a0[s], b0, acc, 0, 0, 0);
                acc = __builtin_amdgcn_mfma_f32_16x16x32_bf16(a1[s], b1, acc, 0, 0, 0);
                if (cg == wr + s * 16) {       // diagonal tile (wave-uniform, rare)
                    // C/D: col = lane&15, row = q*4 + reg
                    #pragma unroll
                    for (int i = 0; i < 4; ++i)
                        if (l15 == q * 4 + i) posv[cg + q * 4 + i] = acc[i];
                }
                sum[s * 4 + 0] += EXP2F(acc[0]);
                sum[s * 4 + 1] += EXP2F(acc[1]);
                sum[s * 4 + 2] += EXP2F(acc[2]);
                sum[s * 4 + 3] += EXP2F(acc[3]);
            }
        }

        if (has_next) {
            char* nbuf = lds + (pb ^ 1) * BUFB;
            *(float4*)(nbuf + gsA * 16) = vA;
            *(float4*)(nbuf + gsB * 16) = vB;
        }
        __syncthreads();
        pb ^= 1;
    }

    // reduce each of the 16 row-sums across the 16 lanes of the quad
    #pragma unroll
    for (int k = 0; k < 16; ++k) {
        float v = sum[k];
        #pragma unroll
        for (int off = 1; off < 16; off <<= 1) v += __shfl_xor(v, off);
        sum[k] = v;
    }
    if (l15 == 0) {
        float* dst = partial + (size_t)blockIdx.y * N + wr;
        #pragma unroll
        for (int s = 0; s < 4; ++s)
            #pragma unroll
            for (int i = 0; i < 4; ++i)
                dst[s * 16 + q * 4 + i] = sum[s * 4 + i];
    }
}

// ---------------------------------------------------------------- finalize
// 64 blocks x 256 threads: thread t handles row blockIdx*256+t (N = 16384).
__global__ __launch_bounds__(256) void finalize_kernel(
    const float* __restrict__ partial, const float* __restrict__ posv,
    float* __restrict__ out, int N)
{
    int row = blockIdx.x * 256 + threadIdx.x;
    float s = 0.f;
    #pragma unroll
    for (int c = 0; c < CS; ++c) s += partial[(size_t)c * N + row];
    float acc = (LOG2F(s) - posv[row]) * (0.69314718055994531f / (float)N);
    #pragma unroll
    for (int off = 32; off; off >>= 1) acc += __shfl_xor(acc, off);
    if ((threadIdx.x & 63) == 0) atomicAdd(out, acc);
}

// ---------------------------------------------------------------- launch
extern "C" void kernel_launch(void* const* d_in, const int* in_sizes, int n_in,
                              void* d_out, int out_size, void* d_ws, size_t ws_size,
                              hipStream_t stream)
{
    const float* z1 = (const float*)d_in[0];
    const float* z2 = (const float*)d_in[1];
    const int N = in_sizes[0] / DDIM;   // 16384

    char* ws = (char*)d_ws;
    __hip_bfloat16* z1s = (__hip_bfloat16*)ws;                  // N*128 B
    __hip_bfloat16* z2s = z1s + (size_t)N * DDIM;               // N*128 B
    float* partial = (float*)(ws + 2 * (size_t)N * ROWB);       // CS*N*4 B
    float* posv    = partial + (size_t)CS * N;                  // N*4 B

    const float kScale = 28.853900817779268f;   // log2(e) / 0.05

    hipMemsetAsync(d_out, 0, sizeof(float), stream);

    norm_both_kernel<<<2 * N / 4, 256, 0, stream>>>(z1, z2, z1s, kScale, N);

    dim3 grid(N / BM, CS);
    infonce_main_kernel<<<grid, NW * 64, 0, stream>>>(z1s, z2s, partial, posv, N);

    finalize_kernel<<<N / 256, 256, 0, stream>>>(partial, posv, (float*)d_out, N);
}

// Round 4
// 115.367 us; speedup vs baseline: 1.3966x; 1.1131x over previous
//
#include <hip/hip_runtime.h>
#include <hip/hip_bf16.h>

// InfoNCE fused: loss = (1/N) sum_i [ log(sum_j exp(sim_ij)) - sim_ii ]
// sim = (z1/||z1||)@(z2/||z2||)^T / tau.  logits=[pos, diag-masked row] with
// pos == sim_ii => lse over the FULL row (diagonal included).
//
// z1f = bf16(z1n * log2(e)/tau) so exp(sim) = exp2(MFMA output); values in
// [-29,29] in log2 domain -> raw v_exp_f32 (__builtin_amdgcn_exp2f), NOT libm.
//
// R4: LDS-free, barrier-free main loop. The norm kernel writes z1f/z2f in
// GLOBAL-MEMORY MFMA FRAGMENT ORDER (per 16-col tile: 2048 B; lane*16 -> b0,
// +1024 -> b1), so the main kernel's A/B loads are single coalesced
// global_load_dwordx4 (L1/L2-hit; 4 waves/block share B tiles). No
// __syncthreads -> no vmcnt(0) drain stalls (the R3 bottleneck: VALUBusy 44%).

typedef __bf16  bf16x8 __attribute__((ext_vector_type(8)));
typedef __bf16  bf16x4 __attribute__((ext_vector_type(4)));
typedef float   f32x4  __attribute__((ext_vector_type(4)));

#if __has_builtin(__builtin_amdgcn_exp2f)
#define EXP2F(x) __builtin_amdgcn_exp2f(x)   // raw v_exp_f32
#else
#define EXP2F(x) exp2f(x)
#endif
#if __has_builtin(__builtin_amdgcn_logf)
#define LOG2F(x) __builtin_amdgcn_logf(x)    // raw v_log_f32
#else
#define LOG2F(x) log2f(x)
#endif

#define DDIM   64
#define TILEB  2048         // bytes per fragment-ordered 16-col tile
#define NSETS  4            // 16-row MFMA sets per wave (64 rows/wave)
#define NW     4            // waves per block
#define BM     (NW * NSETS * 16)   // 256 rows per block
#define CS     32           // column splits -> grid (64,32) = 2048 blocks

// ---------------------------------------------------------------- normalize
// One block per 16-row tile. Thread (r = tid>>4, c = tid&15) loads
// z[row, 4c..4c+4), reduces ||row|| over its 16-lane group, writes the 4
// bf16 values into fragment order:
//   byte off(tile) = (c>>3)*1024 + ((c>>1)&3)*256 + r*16 + (c&1)*8
// Also zeroes rowsum (and d_out from block 0) -- stream-ordered before main.
__global__ __launch_bounds__(256) void norm_frag_kernel(
    const float* __restrict__ z1, const float* __restrict__ z2,
    __hip_bfloat16* __restrict__ z1f, __hip_bfloat16* __restrict__ z2f,
    float* __restrict__ rowsum, float* __restrict__ out,
    float scale1, int N)
{
    const int tid  = threadIdx.x;
    const int r    = tid >> 4, c = tid & 15;
    const int tile = blockIdx.x;
    const size_t row = (size_t)tile * 16 + r;
    const size_t off = (size_t)tile * TILEB
                     + ((c >> 3) << 10) + (((c >> 1) & 3) << 8)
                     + (r << 4) + ((c & 1) << 3);

    // z1 (scaled by log2(e)/tau)
    {
        float4 v = *(const float4*)(z1 + row * DDIM + c * 4);
        float ss = v.x*v.x + v.y*v.y + v.z*v.z + v.w*v.w;
        #pragma unroll
        for (int o = 8; o; o >>= 1) ss += __shfl_xor(ss, o);
        float inv = scale1 / fmaxf(sqrtf(ss), 1e-12f);
        bf16x4 ov = { __float2bfloat16(v.x*inv), __float2bfloat16(v.y*inv),
                      __float2bfloat16(v.z*inv), __float2bfloat16(v.w*inv) };
        *(bf16x4*)((char*)z1f + off) = ov;
    }
    // z2 (unit scale)
    {
        float4 v = *(const float4*)(z2 + row * DDIM + c * 4);
        float ss = v.x*v.x + v.y*v.y + v.z*v.z + v.w*v.w;
        #pragma unroll
        for (int o = 8; o; o >>= 1) ss += __shfl_xor(ss, o);
        float inv = 1.0f / fmaxf(sqrtf(ss), 1e-12f);
        bf16x4 ov = { __float2bfloat16(v.x*inv), __float2bfloat16(v.y*inv),
                      __float2bfloat16(v.z*inv), __float2bfloat16(v.w*inv) };
        *(bf16x4*)((char*)z2f + off) = ov;
    }

    if (tid < 16) rowsum[(size_t)tile * 16 + tid] = 0.f;
    if (tile == 0 && tid == 0) *out = 0.f;
}

// ---------------------------------------------------------------- main
__global__ __launch_bounds__(256) void infonce_main_kernel(
    const __hip_bfloat16* __restrict__ z1f,
    const __hip_bfloat16* __restrict__ z2f,
    float* __restrict__ rowsum,    // fp32, atomic partial rowsums of 2^C
    float* __restrict__ posv,      // C_ii (log2-domain positive logit)
    int N)
{
    const int tid  = threadIdx.x;
    const int wave = tid >> 6;
    const int lane = tid & 63;
    const int q    = lane >> 4;
    const int l15  = lane & 15;

    const int colspan = N / CS;
    const int c0      = blockIdx.y * colspan;
    const int wr      = blockIdx.x * BM + wave * (NSETS * 16);

    // A fragments for NSETS row-tiles (coalesced: fragment-ordered global)
    bf16x8 a0[NSETS], a1[NSETS];
    #pragma unroll
    for (int s = 0; s < NSETS; ++s) {
        const char* ab = (const char*)z1f + (size_t)((wr >> 4) + s) * TILEB + lane * 16;
        a0[s] = *(const bf16x8*)(ab);
        a1[s] = *(const bf16x8*)(ab + 1024);
    }

    float sum[NSETS * 4];
    #pragma unroll
    for (int k = 0; k < NSETS * 4; ++k) sum[k] = 0.f;

    const char* bptr = (const char*)z2f + (size_t)(c0 >> 4) * TILEB + lane * 16;
    const int ntiles = colspan >> 4;

    #pragma unroll 2
    for (int t = 0; t < ntiles; ++t) {
        bf16x8 b0 = *(const bf16x8*)(bptr);
        bf16x8 b1 = *(const bf16x8*)(bptr + 1024);
        bptr += TILEB;
        const int cg = c0 + (t << 4);
        #pragma unroll
        for (int s = 0; s < NSETS; ++s) {
            f32x4 acc = {0.f, 0.f, 0.f, 0.f};
            acc = __builtin_amdgcn_mfma_f32_16x16x32_bf16(a0[s], b0, acc, 0, 0, 0);
            acc = __builtin_amdgcn_mfma_f32_16x16x32_bf16(a1[s], b1, acc, 0, 0, 0);
            if (cg == wr + s * 16) {          // diagonal tile (wave-uniform, rare)
                // C/D: col = lane&15, row = q*4 + reg
                #pragma unroll
                for (int i = 0; i < 4; ++i)
                    if (l15 == q * 4 + i) posv[cg + q * 4 + i] = acc[i];
            }
            sum[s * 4 + 0] += EXP2F(acc[0]);
            sum[s * 4 + 1] += EXP2F(acc[1]);
            sum[s * 4 + 2] += EXP2F(acc[2]);
            sum[s * 4 + 3] += EXP2F(acc[3]);
        }
    }

    // reduce each row-sum across the 16 lanes of the quad, then atomics
    #pragma unroll
    for (int k = 0; k < NSETS * 4; ++k) {
        float v = sum[k];
        #pragma unroll
        for (int o = 1; o < 16; o <<= 1) v += __shfl_xor(v, o);
        sum[k] = v;
    }
    if (l15 == 0) {
        #pragma unroll
        for (int s = 0; s < NSETS; ++s)
            #pragma unroll
            for (int i = 0; i < 4; ++i)
                atomicAdd(&rowsum[wr + s * 16 + q * 4 + i], sum[s * 4 + i]);
    }
}

// ---------------------------------------------------------------- finalize
// 64 blocks x 256 threads: thread t handles one row.
__global__ __launch_bounds__(256) void finalize_kernel(
    const float* __restrict__ rowsum, const float* __restrict__ posv,
    float* __restrict__ out, int N)
{
    int row = blockIdx.x * 256 + threadIdx.x;
    float acc = (LOG2F(rowsum[row]) - posv[row]) * (0.69314718055994531f / (float)N);
    #pragma unroll
    for (int o = 32; o; o >>= 1) acc += __shfl_xor(acc, o);
    if ((threadIdx.x & 63) == 0) atomicAdd(out, acc);
}

// ---------------------------------------------------------------- launch
extern "C" void kernel_launch(void* const* d_in, const int* in_sizes, int n_in,
                              void* d_out, int out_size, void* d_ws, size_t ws_size,
                              hipStream_t stream)
{
    const float* z1 = (const float*)d_in[0];
    const float* z2 = (const float*)d_in[1];
    const int N = in_sizes[0] / DDIM;   // 16384

    char* ws = (char*)d_ws;
    __hip_bfloat16* z1f = (__hip_bfloat16*)ws;                  // N*128 B (2 MB)
    __hip_bfloat16* z2f = z1f + (size_t)N * DDIM;               // N*128 B (2 MB)
    float* rowsum = (float*)(ws + 2 * (size_t)N * DDIM * 2);    // N*4 B
    float* posv   = rowsum + N;                                 // N*4 B

    const float kScale = 28.853900817779268f;   // log2(e) / 0.05

    norm_frag_kernel<<<N / 16, 256, 0, stream>>>(z1, z2, z1f, z2f, rowsum,
                                                 (float*)d_out, kScale, N);

    dim3 grid(N / BM, CS);
    infonce_main_kernel<<<grid, NW * 64, 0, stream>>>(z1f, z2f, rowsum, posv, N);

    finalize_kernel<<<N / 256, 256, 0, stream>>>(rowsum, posv, (float*)d_out, N);
}